// Round 8
// baseline (239.958 us; speedup 1.0000x reference)
//
#include <hip/hip_runtime.h>
#include <hip/hip_bf16.h>

typedef __bf16 bf16_t;
typedef __bf16 bf16x8 __attribute__((ext_vector_type(8)));
typedef float  floatx4 __attribute__((ext_vector_type(4)));

#define BQ 16
#define NTOK 2048

// ---------------- Kernel 0: W -> W^T bf16, + zero out-accumulator & rowsums ----------------
__global__ __launch_bounds__(256) void k_prep(const float* __restrict__ Wq,
                                              const float* __restrict__ Wk,
                                              const float* __restrict__ Wv,
                                              bf16_t* __restrict__ wt,
                                              float* __restrict__ outz,
                                              float* __restrict__ rsz) {
    int o = blockIdx.x * 256 + threadIdx.x;   // grid 1024 -> o < 262144
    if (o < 49152) {
        int w = o >> 14;
        int r = o & 16383;
        int h = r >> 8;
        int d = r & 255;
        const float* W = (w == 0) ? Wq : ((w == 1) ? Wk : Wv);
        wt[o] = (bf16_t)W[d * 64 + h];
    }
    float4 z = make_float4(0.f, 0.f, 0.f, 0.f);
    for (int u = o; u < 532480; u += 262144) {
        if (u < 524288) ((float4*)outz)[u] = z;
        else            ((float4*)rsz)[u - 524288] = z;
    }
}

// ---------------- Kernel 1: QKV projection (32 tokens/block, 1024 blocks) ----------------
#define XS 264
#define VS 40
__global__ __launch_bounds__(256) void k_qkv(const float* __restrict__ x,
                                             const bf16_t* __restrict__ wt,
                                             const float* __restrict__ bq,
                                             const float* __restrict__ bk,
                                             const float* __restrict__ bv,
                                             bf16_t* __restrict__ qb,
                                             bf16_t* __restrict__ kb,
                                             bf16_t* __restrict__ vt) {
    __shared__ bf16_t x_ls[32 * XS];
    __shared__ bf16_t vt_ls[64 * VS];

    int b  = blockIdx.x >> 6;
    int t0 = (blockIdx.x & 63) << 5;
    int t  = threadIdx.x;
    int lane = t & 63;
    int w    = t >> 6;
    int m_   = lane & 15;
    int q4   = lane >> 4;

    for (int tau = t; tau < 2048; tau += 256) {
        int row = tau >> 6, ch = tau & 63;
        float4 v = ((const float4*)x)[(size_t)(b * NTOK + t0 + row) * 64 + ch];
        bf16_t tmp[4] = {(bf16_t)v.x, (bf16_t)v.y, (bf16_t)v.z, (bf16_t)v.w};
        *(uint2*)(&x_ls[row * XS + ch * 4]) = *(uint2*)tmp;
    }
    __syncthreads();

    for (int wi = 0; wi < 3; ++wi) {
        const bf16_t* wtw = wt + wi * 16384;
        floatx4 acc[2];
        #pragma unroll
        for (int mt = 0; mt < 2; ++mt) acc[mt] = floatx4{0.f, 0.f, 0.f, 0.f};

        #pragma unroll
        for (int ks = 0; ks < 8; ++ks) {
            bf16x8 bfrag = *(const bf16x8*)(wtw + (16 * w + m_) * 256 + ks * 32 + q4 * 8);
            #pragma unroll
            for (int mt = 0; mt < 2; ++mt) {
                bf16x8 afrag = *(const bf16x8*)(&x_ls[(16 * mt + m_) * XS + ks * 32 + q4 * 8]);
                acc[mt] = __builtin_amdgcn_mfma_f32_16x16x32_bf16(afrag, bfrag, acc[mt], 0, 0, 0);
            }
        }
        const float* bias_p = (wi == 0) ? bq : ((wi == 1) ? bk : bv);
        float bias = bias_p[16 * w + m_];
        float scale = (wi == 0) ? 0.125f : 1.0f;   // fold H^-0.5 into q (exact pow2)

        if (wi < 2) {
            bf16_t* dst = (wi == 0) ? qb : kb;
            #pragma unroll
            for (int mt = 0; mt < 2; ++mt)
                #pragma unroll
                for (int r = 0; r < 4; ++r) {
                    int tok = t0 + 16 * mt + 4 * q4 + r;
                    dst[(size_t)(b * NTOK + tok) * 64 + 16 * w + m_] = (bf16_t)((acc[mt][r] + bias) * scale);
                }
        } else {
            #pragma unroll
            for (int mt = 0; mt < 2; ++mt)
                #pragma unroll
                for (int r = 0; r < 4; ++r)
                    vt_ls[(16 * w + m_) * VS + 16 * mt + 4 * q4 + r] = (bf16_t)(acc[mt][r] + bias);
            __syncthreads();
            {
                int h = t >> 2, ch = t & 3;
                uint4 val = *(const uint4*)(&vt_ls[h * VS + ch * 8]);
                *(uint4*)(vt + (size_t)(b * 64 + h) * NTOK + t0 + ch * 8) = val;
            }
        }
    }
}

// ---------------- Kernel 2: fused attention, register fp32 conv, no A/K/V LDS ----------------
// frame: 48 rows (46bx-1 .. 46bx+46, interior 1..46) x 64 cols (fs .. fs+63, interior 1..62)
// fs = 62*it - 2.  34 col-iters, split into 3 chunks of <=12.
#define PS 72     // p_ls stride (bf16)
#define NITC 34
#define CHUNK 12
#define GX 45
__global__ __launch_bounds__(256) void k_attn(const bf16_t* __restrict__ qb,
                                              const bf16_t* __restrict__ kb,
                                              const bf16_t* __restrict__ vt,
                                              const float* __restrict__ conv_w,
                                              const float* __restrict__ conv_b,
                                              float* __restrict__ outp,
                                              float* __restrict__ rsg) {
    __shared__ __align__(16) char smem[12288];
    bf16_t* pls    = (bf16_t*)smem;            // [48][PS] bf16 : 6912 B
    float*  seamG0 = (float*)(smem + 6912);    // [4][48]       : 768 B  (wave w's G0 at m_=15)
    float*  seamG2 = (float*)(smem + 7680);    // [4][48]       : 768 B  (wave w's G2 at m_=0)
    float*  scr    = (float*)smem;             // epilogue overlay [48][64] : 12288 B

    int b  = blockIdx.z;
    int bx = blockIdx.x;
    int it0   = blockIdx.y * CHUNK;
    int itEnd = (it0 + CHUNK < NITC) ? (it0 + CHUNK) : NITC;
    int t = threadIdx.x, lane = t & 63, w = t >> 6;
    int m_ = lane & 15, q4 = lane >> 4;

    float cw[9];
    #pragma unroll
    for (int i = 0; i < 9; ++i) cw[i] = conv_w[i];
    float cb = conv_b[0];

    // ---- one-time: q fragments (A-operand), direct from global ----
    bf16x8 qf[3][2];
    {
        int tokq = 46 * bx - 1 + m_;
        #pragma unroll
        for (int si = 0; si < 3; ++si) {
            int tok = tokq + 16 * si;
            bool ok = (tok >= 0) && (tok < NTOK);
            #pragma unroll
            for (int ks = 0; ks < 2; ++ks) {
                bf16x8 v = {};
                if (ok) v = *(const bf16x8*)(qb + ((size_t)(b * NTOK + tok)) * 64 + ks * 32 + q4 * 8);
                qf[si][ks] = v;
            }
        }
    }

    bool rimcol = ((w == 0) && (m_ == 0)) || ((w == 3) && (m_ == 15));

    floatx4 accO[3];
    #pragma unroll
    for (int si = 0; si < 3; ++si) accO[si] = floatx4{0.f, 0.f, 0.f, 0.f};
    float rs[3][4] = {};

    const bf16_t* kbb = kb + (size_t)b * NTOK * 64;
    const bf16_t* vtb = vt + (size_t)b * 64 * NTOK;
    size_t vrow = (size_t)(16 * w + m_) * NTOK;

    // k: B-frag = K[tok=fs+16w+m_][h=32ks+8q4+j]; v: B-frag = V[tok=fs+32ks+8q4+j][h=16w+m_]
    bf16x8 kf[2], vf[2];
    auto load_kv = [&](int it, bf16x8* kd, bf16x8* vd) {
        int fs = 62 * it - 2;
        int tok = fs + 16 * w + m_;
        bool ok = (tok >= 0) && (tok < NTOK);
        #pragma unroll
        for (int ks = 0; ks < 2; ++ks) {
            bf16x8 v = {};
            if (ok) v = *(const bf16x8*)(kbb + (size_t)tok * 64 + ks * 32 + q4 * 8);
            kd[ks] = v;
        }
        #pragma unroll
        for (int ks = 0; ks < 2; ++ks) {
            int col = fs + 32 * ks + 8 * q4;
            if (col < 0 || col > NTOK - 8) {
                // EXACT per-element gather on BOTH edges: vd[j] must be V[col+j]
                // (0 for OOB). Base-clamping misaligns V against P wherever the
                // fragment straddles the boundary with valid tokens — this was
                // the R5 (low-end) and R6/R7 (high-end, it=33 col=2044) bug.
                bf16x8 v = {};
                #pragma unroll
                for (int j = 0; j < 8; ++j) {
                    int tk = col + j;
                    if (tk >= 0 && tk < NTOK) v[j] = vtb[vrow + tk];
                }
                vd[ks] = v;
            } else {
                vd[ks] = *(const bf16x8*)(vtb + vrow + col);
            }
        }
    };
    load_kv(it0, kf, vf);

    for (int it = it0; it < itEnd; ++it) {
        // ---- A: QK^T (regs) ----
        floatx4 Cq[3];
        #pragma unroll
        for (int si = 0; si < 3; ++si) {
            floatx4 c = floatx4{0.f, 0.f, 0.f, 0.f};
            #pragma unroll
            for (int ks = 0; ks < 2; ++ks)
                c = __builtin_amdgcn_mfma_f32_16x16x32_bf16(qf[si][ks], kf[ks], c, 0, 0, 0);
            Cq[si] = c;
        }

        // ---- register conv, rank-3 decomposition, exact fp32 ----
        float cp[3][4];
        #pragma unroll
        for (int si = 0; si < 3; ++si) {
            // row neighbors: up=row f-1, dn=row f+1 at same col
            float a_up = __shfl(Cq[si][3], lane - 16);                       // valid q4>0
            float b_up = (si > 0) ? __shfl(Cq[si - 1][3], lane + 48) : 0.f;  // valid q4==0
            float c_dn = __shfl(Cq[si][0], lane + 16);                       // valid q4<3
            float d_dn = (si < 2) ? __shfl(Cq[si + 1][0], lane - 48) : 0.f;  // valid q4==3
            float up[4], dn[4];
            up[0] = (q4 > 0) ? a_up : b_up;   // si==0,q4==0 -> 0 (global row pad)
            up[1] = Cq[si][0]; up[2] = Cq[si][1]; up[3] = Cq[si][2];
            dn[0] = Cq[si][1]; dn[1] = Cq[si][2]; dn[2] = Cq[si][3];
            dn[3] = (q4 < 3) ? c_dn : d_dn;   // si==2,q4==3 -> 0 (only feeds masked f=47)

            float G0[4], G1[4], G2[4];
            #pragma unroll
            for (int r = 0; r < 4; ++r) {
                float cu = Cq[si][r];
                G0[r] = cw[0] * up[r] + cw[3] * cu + cw[6] * dn[r];
                G1[r] = cw[1] * up[r] + cw[4] * cu + cw[7] * dn[r];
                G2[r] = cw[2] * up[r] + cw[5] * cu + cw[8] * dn[r];
            }
            // col combine: conv[n] = G0[n-1] + G1[n] + G2[n+1]
            #pragma unroll
            for (int r = 0; r < 4; ++r) {
                float e0 = __shfl(G0[r], lane - 1);   // valid m_>=1
                float e2 = __shfl(G2[r], lane + 1);   // valid m_<=14
                cp[si][r] = G1[r] + ((m_ >= 1) ? e0 : 0.f) + ((m_ <= 14) ? e2 : 0.f);
            }
            // strip-seam export (cross-wave neighbors)
            if (m_ == 15) {
                float4 tv = make_float4(G0[0], G0[1], G0[2], G0[3]);
                *(float4*)&seamG0[w * 48 + 16 * si + 4 * q4] = tv;
            }
            if (m_ == 0) {
                float4 tv = make_float4(G2[0], G2[1], G2[2], G2[3]);
                *(float4*)&seamG2[w * 48 + 16 * si + 4 * q4] = tv;
            }
        }
        __syncthreads();   // seams visible; prev-iter PV reads of pls done

        // ---- B: prefetch next K/V (latency overlaps elementwise) ----
        bf16x8 kn[2] = {}, vn[2] = {};
        bool pf = (it + 1 < itEnd);
        if (pf) load_kv(it + 1, kn, vn);

        #pragma unroll
        for (int si = 0; si < 3; ++si) {
            if (m_ == 0 && w > 0) {
                float4 s0 = *(const float4*)&seamG0[(w - 1) * 48 + 16 * si + 4 * q4];
                cp[si][0] += s0.x; cp[si][1] += s0.y; cp[si][2] += s0.z; cp[si][3] += s0.w;
            }
            if (m_ == 15 && w < 3) {
                float4 s2 = *(const float4*)&seamG2[(w + 1) * 48 + 16 * si + 4 * q4];
                cp[si][0] += s2.x; cp[si][1] += s2.y; cp[si][2] += s2.z; cp[si][3] += s2.w;
            }
            #pragma unroll
            for (int r = 0; r < 4; ++r) {
                float conv = cp[si][r] + cb;
                float sig = __builtin_amdgcn_rcpf(1.f + __expf(-conv));
                float s = fmaxf(Cq[si][r] - sig, 0.f);
                float ev = __expf(s) - 1.f;
                if (rimcol) ev = 0.f;
                rs[si][r] += ev;
                pls[(16 * si + 4 * q4 + r) * PS + 16 * w + m_] = (bf16_t)ev;
            }
        }
        __syncthreads();   // pls ready; seam reads done before next overwrite

        // ---- C: PV: O[48x64] += P @ V ----
        #pragma unroll
        for (int ks = 0; ks < 2; ++ks)
            #pragma unroll
            for (int si = 0; si < 3; ++si) {
                bf16x8 af = *(const bf16x8*)(pls + (16 * si + m_) * PS + ks * 32 + q4 * 8);
                accO[si] = __builtin_amdgcn_mfma_f32_16x16x32_bf16(af, vf[ks], accO[si], 0, 0, 0);
            }
        if (pf) {
            #pragma unroll
            for (int ks = 0; ks < 2; ++ks) { kf[ks] = kn[ks]; vf[ks] = vn[ks]; }
        }
    }

    // ---- epilogue: rowsum reduce via scr overlay, then atomics ----
    __syncthreads();
    #pragma unroll
    for (int si = 0; si < 3; ++si)
        #pragma unroll
        for (int r = 0; r < 4; ++r)
            scr[(16 * si + 4 * q4 + r) * 64 + 16 * w + m_] = rs[si][r];
    __syncthreads();
    if (t < 46) {
        int grow = 46 * bx + t;
        if (grow < NTOK) {
            const float4* p4 = (const float4*)(scr + (t + 1) * 64);
            float s = 0.f;
            #pragma unroll
            for (int j = 0; j < 16; ++j) { float4 v = p4[j]; s += v.x + v.y + v.z + v.w; }
            atomicAdd(&rsg[b * NTOK + grow], s);
        }
    }
    #pragma unroll
    for (int si = 0; si < 3; ++si)
        #pragma unroll
        for (int r = 0; r < 4; ++r) {
            int f = 16 * si + 4 * q4 + r;
            int grow = 46 * bx - 1 + f;
            if (f >= 1 && f < 47 && grow < NTOK)
                atomicAdd(outp + ((size_t)(b * NTOK + grow)) * 64 + 16 * w + m_, accO[si][r]);
        }
}

// ---------------- Kernel 3: normalize out /= (rowsum + eps), in place ----------------
__global__ __launch_bounds__(256) void k_norm(float* __restrict__ out,
                                              const float* __restrict__ rsg) {
    int gid = blockIdx.x * 256 + threadIdx.x;   // 524288 float4s
    float4 o = ((float4*)out)[gid];
    float d = rsg[gid >> 4] + 1e-5f;
    float inv = 1.f / d;
    o.x *= inv; o.y *= inv; o.z *= inv; o.w *= inv;
    ((float4*)out)[gid] = o;
}

extern "C" void kernel_launch(void* const* d_in, const int* in_sizes, int n_in,
                              void* d_out, int out_size, void* d_ws, size_t ws_size,
                              hipStream_t stream) {
    const float* x  = (const float*)d_in[0];
    const float* Wq = (const float*)d_in[1];
    const float* bq = (const float*)d_in[2];
    const float* Wk = (const float*)d_in[3];
    const float* bk = (const float*)d_in[4];
    const float* Wv = (const float*)d_in[5];
    const float* bv = (const float*)d_in[6];
    const float* cw = (const float*)d_in[7];
    const float* cb = (const float*)d_in[8];
    float* out = (float*)d_out;

    char* ws = (char*)d_ws;
    bf16_t* wt = (bf16_t*)ws;                               // 96 KB
    bf16_t* qb = (bf16_t*)(ws + 98304);                     // 4 MB
    bf16_t* kb = (bf16_t*)(ws + 98304 + 4194304);           // 4 MB
    bf16_t* vt = (bf16_t*)(ws + 98304 + 8388608);           // 4 MB
    float*  rsg = (float*)(ws + 98304 + 12582912);          // 128 KB

    k_prep<<<dim3(1024), dim3(256), 0, stream>>>(Wq, Wk, Wv, wt, out, rsg);
    k_qkv<<<dim3(1024), dim3(256), 0, stream>>>(x, wt, bq, bk, bv, qb, kb, vt);
    k_attn<<<dim3(GX, 3, BQ), dim3(256), 0, stream>>>(qb, kb, vt, cw, cb, out, rsg);
    k_norm<<<dim3(2048), dim3(256), 0, stream>>>(out, rsg);
}